// Round 1
// baseline (27110.049 us; speedup 1.0000x reference)
//
#include <hip/hip_runtime.h>
#include <hip/hip_fp16.h>

#define F_DIM 510
#define KP    512      // padded K
#define B_SZ  256
#define T_ST  512
#define MB    64       // batch rows per WG
#define NWG   256

typedef _Float16 h8 __attribute__((ext_vector_type(8)));
typedef float    f4 __attribute__((ext_vector_type(4)));

__device__ __forceinline__ float sigm(float v)   { return 1.0f / (1.0f + __expf(-v)); }
__device__ __forceinline__ float tanh_f(float v) { return 1.0f - 2.0f / (__expf(2.0f * v) + 1.0f); }

__global__ void init_kernel(float* __restrict__ out, const float* __restrict__ b_lin,
                            int* __restrict__ bar) {
  int i = blockIdx.x * blockDim.x + threadIdx.x;
  if (i == 0) { bar[0] = 0; bar[1] = 0; }
  if (i < B_SZ * T_ST) out[i] = b_lin[0];
}

// stage fp32 source [MB][F_DIM] -> LDS fp16 [MB][KP], XOR-swizzled
__device__ __forceinline__ void stage_x(char* st, const float* __restrict__ src, int tid) {
  #pragma unroll
  for (int i = 0; i < 16; ++i) {
    int c  = tid + (i << 8);
    int m  = c >> 6;
    int kb = (c & 63) << 3;
    h8 v;
    const float* s = src + m * F_DIM + kb;
    if (kb + 8 <= F_DIM) {
      #pragma unroll
      for (int e = 0; e < 4; ++e) {
        float2 p = *(const float2*)(s + 2 * e);
        v[2 * e]     = (_Float16)p.x;
        v[2 * e + 1] = (_Float16)p.y;
      }
    } else {
      #pragma unroll
      for (int e = 0; e < 8; ++e) v[e] = (_Float16)((kb + e < F_DIM) ? s[e] : 0.0f);
    }
    int byte = ((m * KP + kb) << 1) ^ ((m & 7) << 4);
    *(h8*)(st + byte) = v;
  }
}

// stage fp16 source [MB][KP] -> LDS fp16 [MB][KP], XOR-swizzled
__device__ __forceinline__ void stage_h(char* st, const _Float16* __restrict__ src, int tid) {
  #pragma unroll
  for (int i = 0; i < 16; ++i) {
    int c  = tid + (i << 8);
    int m  = c >> 6;
    int kb = (c & 63) << 3;
    uint4 v = *(const uint4*)(src + m * KP + kb);
    int byte = ((m * KP + kb) << 1) ^ ((m & 7) << 4);
    *(uint4*)(st + byte) = v;
  }
}

__device__ __forceinline__ void gbar(int* bar, int target) {
  __syncthreads();
  if (threadIdx.x == 0) {
    __threadfence();
    int prev = __hip_atomic_fetch_add(&bar[0], 1, __ATOMIC_ACQ_REL, __HIP_MEMORY_SCOPE_AGENT);
    if (prev == NWG - 1) {
      __hip_atomic_store(&bar[0], 0, __ATOMIC_RELAXED, __HIP_MEMORY_SCOPE_AGENT);
      __hip_atomic_store(&bar[1], target, __ATOMIC_RELEASE, __HIP_MEMORY_SCOPE_AGENT);
    } else {
      while (__hip_atomic_load(&bar[1], __ATOMIC_ACQUIRE, __HIP_MEMORY_SCOPE_AGENT) < target)
        __builtin_amdgcn_s_sleep(2);
    }
    __threadfence();
  }
  __syncthreads();
}

__launch_bounds__(256, 1)
__global__ void lstm_kernel(
    const float* __restrict__ x,
    const float* __restrict__ w_ih1, const float* __restrict__ w_hh1,
    const float* __restrict__ b_ih1, const float* __restrict__ b_hh1,
    const float* __restrict__ w_ih2, const float* __restrict__ w_hh2,
    const float* __restrict__ b_ih2, const float* __restrict__ b_hh2,
    const float* __restrict__ w_lin,
    float* __restrict__ out, char* __restrict__ ws)
{
  __shared__ __align__(16) char smem[MB * KP * 2];   // 64 KiB operand stage
  float (*gbuf)[MB][17] = (float (*)[MB][17])smem;   // aliased gate exchange (17 KiB)

  int* bar = (int*)ws;
  _Float16* h1 = (_Float16*)(ws + 256);                          // [2][B_SZ][KP]
  _Float16* h2 = (_Float16*)(ws + 256 + 2 * B_SZ * KP * 2);      // [2][B_SZ][KP]

  const int tid  = threadIdx.x;
  const int lane = tid & 63;
  const int wave = tid >> 6;           // wave owns gate type `wave` (i,f,g,o)
  const int wg   = blockIdx.x;
  const bool isL2 = (wg >= 128);
  const int wgl  = wg & 127;
  const int nb   = wgl & 31;           // hidden block (16 units)
  const int mb   = wgl >> 5;           // batch chunk (64 rows)
  const int j0   = nb << 4;
  const int col  = lane & 15;
  const int krow = lane >> 4;
  const int jj   = j0 + col;
  const bool jvalid = (jj < F_DIM);

  const float* wA = isL2 ? w_ih2 : w_ih1;   // first GEMM weights (x or h1 input)
  const float* wB = isL2 ? w_hh2 : w_hh1;   // recurrent weights
  const float* bi = isL2 ? b_ih2 : b_ih1;
  const float* bh = isL2 ? b_hh2 : b_hh1;
  const int nrow  = wave * F_DIM + jj;      // gate row in [2040]

  // B-fragments (weights) resident in registers: B[k][n] = W[n][k]
  h8 wfA[16], wfB[16];
  #pragma unroll
  for (int ks = 0; ks < 16; ++ks) {
    h8 a, b;
    #pragma unroll
    for (int e = 0; e < 8; ++e) {
      int k = (ks << 5) + (krow << 3) + e;
      bool ok = jvalid && (k < F_DIM);
      a[e] = (_Float16)(ok ? wA[nrow * F_DIM + k] : 0.0f);
      b[e] = (_Float16)(ok ? wB[nrow * F_DIM + k] : 0.0f);
    }
    wfA[ks] = a; wfB[ks] = b;
  }
  const float bias = jvalid ? (bi[nrow] + bh[nrow]) : 0.0f;
  const float wl   = (isL2 && jvalid) ? w_lin[jj] : 0.0f;

  float cst[4] = {0.f, 0.f, 0.f, 0.f};

  for (int p = 0; p <= T_ST; ++p) {
    const bool active = isL2 ? (p >= 1) : (p < T_ST);
    if (active) {
      const int t = isL2 ? (p - 1) : p;
      f4 acc[4];
      #pragma unroll
      for (int mt = 0; mt < 4; ++mt) acc[mt] = (f4){bias, bias, bias, bias};

      // ---- GEMM 1: input path (L1: x(t) @ w_ih1^T ; L2: h1(t) @ w_ih2^T) ----
      if (!isL2) {
        stage_x(smem, x + ((size_t)t * B_SZ + mb * MB) * F_DIM, tid);
      } else {
        stage_h(smem, h1 + ((size_t)((p - 1) & 1) * B_SZ + mb * MB) * KP, tid);
      }
      __syncthreads();
      #pragma unroll
      for (int ks = 0; ks < 16; ++ks) {
        #pragma unroll
        for (int mt = 0; mt < 4; ++mt) {
          int lin = mt * (16 * KP * 2) + col * (KP * 2) + ks * 64 + krow * 16;
          h8 af = *(const h8*)(smem + (lin ^ ((col & 7) << 4)));
          acc[mt] = __builtin_amdgcn_mfma_f32_16x16x32_f16(af, wfA[ks], acc[mt], 0, 0, 0);
        }
      }
      __syncthreads();

      // ---- GEMM 2: recurrent path (L1: h1(t-1) @ w_hh1^T ; L2: h2(t-1) @ w_hh2^T) ----
      const bool haveR = isL2 ? (p >= 2) : (p >= 1);
      if (haveR) {
        const _Float16* hs = isL2
            ? (h2 + ((size_t)(p & 1) * B_SZ + mb * MB) * KP)
            : (h1 + ((size_t)((p - 1) & 1) * B_SZ + mb * MB) * KP);
        stage_h(smem, hs, tid);
        __syncthreads();
        #pragma unroll
        for (int ks = 0; ks < 16; ++ks) {
          #pragma unroll
          for (int mt = 0; mt < 4; ++mt) {
            int lin = mt * (16 * KP * 2) + col * (KP * 2) + ks * 64 + krow * 16;
            h8 af = *(const h8*)(smem + (lin ^ ((col & 7) << 4)));
            acc[mt] = __builtin_amdgcn_mfma_f32_16x16x32_f16(af, wfB[ks], acc[mt], 0, 0, 0);
          }
        }
      }
      __syncthreads();   // all stage reads done; smem reused as gate-exchange

      // gate exchange: acc (row=(lane>>4)*4+r, col=lane&15 within tile mt)
      #pragma unroll
      for (int mt = 0; mt < 4; ++mt) {
        #pragma unroll
        for (int r = 0; r < 4; ++r)
          gbuf[wave][mt * 16 + (krow << 2) + r][col] = acc[mt][r];
      }
      __syncthreads();

      // cell update: thread owns (bl = wave*16 + krow*4 + r, column jj)
      _Float16* hdst = isL2 ? (h2 + (size_t)((p - 1) & 1) * B_SZ * KP)
                            : (h1 + (size_t)(p & 1) * B_SZ * KP);
      #pragma unroll
      for (int r = 0; r < 4; ++r) {
        int bl = (wave << 4) + (krow << 2) + r;
        float gi = gbuf[0][bl][col];
        float gf = gbuf[1][bl][col];
        float gg = gbuf[2][bl][col];
        float go = gbuf[3][bl][col];
        float cn = sigm(gf) * cst[r] + sigm(gi) * tanh_f(gg);
        cst[r] = cn;
        float hv = sigm(go) * tanh_f(cn);
        int bg = mb * MB + bl;
        if (jvalid) hdst[(size_t)bg * KP + jj] = (_Float16)hv;
        if (isL2) {
          float part = hv * wl;
          part += __shfl_xor(part, 1);
          part += __shfl_xor(part, 2);
          part += __shfl_xor(part, 4);
          part += __shfl_xor(part, 8);
          if (col == 0) atomicAdd(out + (size_t)bg * T_ST + t, part);
        }
      }
    }
    gbar(bar, p + 1);
  }
}

extern "C" void kernel_launch(void* const* d_in, const int* in_sizes, int n_in,
                              void* d_out, int out_size, void* d_ws, size_t ws_size,
                              hipStream_t stream) {
  (void)in_sizes; (void)n_in; (void)out_size; (void)ws_size;
  const float* x     = (const float*)d_in[0];
  const float* w_ih1 = (const float*)d_in[1];
  const float* w_hh1 = (const float*)d_in[2];
  const float* b_ih1 = (const float*)d_in[3];
  const float* b_hh1 = (const float*)d_in[4];
  const float* w_ih2 = (const float*)d_in[5];
  const float* w_hh2 = (const float*)d_in[6];
  const float* b_ih2 = (const float*)d_in[7];
  const float* b_hh2 = (const float*)d_in[8];
  const float* w_lin = (const float*)d_in[9];
  const float* b_lin = (const float*)d_in[10];
  float* out = (float*)d_out;
  char* ws   = (char*)d_ws;

  hipLaunchKernelGGL(init_kernel, dim3((B_SZ * T_ST + 255) / 256), dim3(256), 0, stream,
                     out, b_lin, (int*)ws);
  hipLaunchKernelGGL(lstm_kernel, dim3(NWG), dim3(256), 0, stream,
                     x, w_ih1, w_hh1, b_ih1, b_hh1,
                     w_ih2, w_hh2, b_ih2, b_hh2,
                     w_lin, out, ws);
}

// Round 2
// 13902.892 us; speedup vs baseline: 1.9500x; 1.9500x over previous
//
#include <hip/hip_runtime.h>
#include <hip/hip_fp16.h>

#define F_DIM 510
#define KP    512      // padded K
#define B_SZ  256
#define T_ST  512
#define MB    64       // batch rows per WG
#define NWG   256

typedef _Float16 h8 __attribute__((ext_vector_type(8)));
typedef float    f4 __attribute__((ext_vector_type(4)));

__device__ __forceinline__ float sigm(float v)   { return 1.0f / (1.0f + __expf(-v)); }
__device__ __forceinline__ float tanh_f(float v) { return 1.0f - 2.0f / (__expf(2.0f * v) + 1.0f); }

__global__ void init_kernel(float* __restrict__ out, const float* __restrict__ b_lin,
                            int* __restrict__ slots) {
  int i = blockIdx.x * blockDim.x + threadIdx.x;
  if (i < NWG) slots[i] = 0;
  if (i < B_SZ * T_ST) out[i] = b_lin[0];
}

// stage fp32 source [MB][F_DIM] -> LDS fp16 [MB][KP], XOR-swizzled (plain cached loads; x is immutable)
__device__ __forceinline__ void stage_x(char* st, const float* __restrict__ src, int tid) {
  #pragma unroll
  for (int i = 0; i < 16; ++i) {
    int c  = tid + (i << 8);
    int m  = c >> 6;
    int kb = (c & 63) << 3;
    h8 v;
    const float* s = src + m * F_DIM + kb;
    if (kb + 8 <= F_DIM) {
      #pragma unroll
      for (int e = 0; e < 4; ++e) {
        float2 p = *(const float2*)(s + 2 * e);
        v[2 * e]     = (_Float16)p.x;
        v[2 * e + 1] = (_Float16)p.y;
      }
    } else {
      #pragma unroll
      for (int e = 0; e < 8; ++e) v[e] = (_Float16)((kb + e < F_DIM) ? s[e] : 0.0f);
    }
    int byte = ((m * KP + kb) << 1) ^ ((m & 7) << 4);
    *(h8*)(st + byte) = v;
  }
}

// stage fp16 h-state [MB][KP] -> LDS, XOR-swizzled. Agent-scope loads (bypass stale L1/L2):
// h is cross-WG data exchanged through the L3 coherence point.
__device__ __forceinline__ void stage_h_coh(char* st, const _Float16* __restrict__ src, int tid) {
  #pragma unroll
  for (int i = 0; i < 32; ++i) {
    int c  = tid + (i << 8);          // 0..8191 : 8-byte chunk index
    int m  = c >> 7;                  // row 0..63
    int kc = c & 127;                 // 8B chunk within row (row = 1024 B)
    unsigned long long v = __hip_atomic_load(
        (const unsigned long long*)(src + (size_t)m * KP) + kc,
        __ATOMIC_RELAXED, __HIP_MEMORY_SCOPE_AGENT);
    int byte = ((m * KP) << 1) + (kc << 3);
    byte ^= (m & 7) << 4;
    *(unsigned long long*)(st + byte) = v;
  }
}

__launch_bounds__(256, 1)
__global__ void lstm_kernel(
    const float* __restrict__ x,
    const float* __restrict__ w_ih1, const float* __restrict__ w_hh1,
    const float* __restrict__ b_ih1, const float* __restrict__ b_hh1,
    const float* __restrict__ w_ih2, const float* __restrict__ w_hh2,
    const float* __restrict__ b_ih2, const float* __restrict__ b_hh2,
    const float* __restrict__ w_lin,
    float* __restrict__ out, char* __restrict__ ws)
{
  __shared__ __align__(16) char smem[MB * KP * 2];   // 64 KiB operand stage
  float (*gbuf)[MB][17] = (float (*)[MB][17])smem;   // aliased gate exchange

  int* slots   = (int*)ws;                                        // [NWG]
  _Float16* h1 = (_Float16*)(ws + 1024);                          // [2][B_SZ][KP]
  _Float16* h2 = (_Float16*)(ws + 1024 + 2 * B_SZ * KP * 2);      // [2][B_SZ][KP]

  const int tid  = threadIdx.x;
  const int lane = tid & 63;
  const int wave = tid >> 6;           // wave owns gate type (i,f,g,o)
  const int wg   = blockIdx.x;
  // XCD pinning: wg%8 = XCD (round-robin dispatch). Chunk c -> XCD pair {2c,2c+1},
  // L1 on even XCD, L2 on odd. Pure remap (bijective) -> correctness-neutral.
  const int xcd   = wg & 7;
  const bool isL2 = (xcd & 1) != 0;
  const int mb    = xcd >> 1;          // batch chunk 0..3 (64 rows each)
  const int nb    = wg >> 3;           // hidden block 0..31 (16 units)
  const int slot_idx = (mb << 6) + (isL2 ? 32 : 0) + nb;

  const int j0   = nb << 4;
  const int col  = lane & 15;
  const int krow = lane >> 4;
  const int jj   = j0 + col;
  const bool jvalid = (jj < F_DIM);

  const float* wA = isL2 ? w_ih2 : w_ih1;
  const float* wB = isL2 ? w_hh2 : w_hh1;
  const float* bi = isL2 ? b_ih2 : b_ih1;
  const float* bh = isL2 ? b_hh2 : b_hh1;
  const int nrow  = wave * F_DIM + jj;

  // Weights resident in registers as MFMA B-fragments: B[k][n] = W[n][k]
  h8 wfA[16], wfB[16];
  #pragma unroll
  for (int ks = 0; ks < 16; ++ks) {
    h8 a, b;
    #pragma unroll
    for (int e = 0; e < 8; ++e) {
      int k = (ks << 5) + (krow << 3) + e;
      bool ok = jvalid && (k < F_DIM);
      a[e] = (_Float16)(ok ? wA[nrow * F_DIM + k] : 0.0f);
      b[e] = (_Float16)(ok ? wB[nrow * F_DIM + k] : 0.0f);
    }
    wfA[ks] = a; wfB[ks] = b;
  }
  const float bias = jvalid ? (bi[nrow] + bh[nrow]) : 0.0f;
  const float wl   = (isL2 && jvalid) ? w_lin[jj] : 0.0f;

  float cst[4] = {0.f, 0.f, 0.f, 0.f};

  for (int p = 0; p <= T_ST; ++p) {
    const bool active = isL2 ? (p >= 1) : (p < T_ST);
    if (active) {
      const int t = isL2 ? (p - 1) : p;
      f4 acc[4];
      #pragma unroll
      for (int mt = 0; mt < 4; ++mt) acc[mt] = (f4){bias, bias, bias, bias};

      // ---- GEMM 1: input path (L1: x(t) ; L2: h1(t)) ----
      if (!isL2) {
        stage_x(smem, x + ((size_t)t * B_SZ + mb * MB) * F_DIM, tid);
      } else {
        stage_h_coh(smem, h1 + ((size_t)((p - 1) & 1) * B_SZ + mb * MB) * KP, tid);
      }
      __syncthreads();
      #pragma unroll
      for (int ks = 0; ks < 16; ++ks) {
        #pragma unroll
        for (int mt = 0; mt < 4; ++mt) {
          int lin = mt * (16 * KP * 2) + col * (KP * 2) + ks * 64 + krow * 16;
          h8 af = *(const h8*)(smem + (lin ^ ((col & 7) << 4)));
          acc[mt] = __builtin_amdgcn_mfma_f32_16x16x32_f16(af, wfA[ks], acc[mt], 0, 0, 0);
        }
      }
      __syncthreads();

      // ---- GEMM 2: recurrent path (L1: h1(t-1) ; L2: h2(t-1)) ----
      const bool haveR = isL2 ? (p >= 2) : (p >= 1);
      if (haveR) {
        const _Float16* hs = isL2
            ? (h2 + ((size_t)(p & 1) * B_SZ + mb * MB) * KP)
            : (h1 + ((size_t)((p - 1) & 1) * B_SZ + mb * MB) * KP);
        stage_h_coh(smem, hs, tid);
        __syncthreads();
        #pragma unroll
        for (int ks = 0; ks < 16; ++ks) {
          #pragma unroll
          for (int mt = 0; mt < 4; ++mt) {
            int lin = mt * (16 * KP * 2) + col * (KP * 2) + ks * 64 + krow * 16;
            h8 af = *(const h8*)(smem + (lin ^ ((col & 7) << 4)));
            acc[mt] = __builtin_amdgcn_mfma_f32_16x16x32_f16(af, wfB[ks], acc[mt], 0, 0, 0);
          }
        }
      }
      __syncthreads();   // stage reads done; smem reused as gate-exchange

      // gate exchange
      #pragma unroll
      for (int mt = 0; mt < 4; ++mt) {
        #pragma unroll
        for (int r = 0; r < 4; ++r)
          gbuf[wave][mt * 16 + (krow << 2) + r][col] = acc[mt][r];
      }
      __syncthreads();

      // cell update: thread owns (bl = wave*16 + krow*4 + r, column jj)
      _Float16* hdst = isL2 ? (h2 + (size_t)((p - 1) & 1) * B_SZ * KP)
                            : (h1 + (size_t)(p & 1) * B_SZ * KP);
      #pragma unroll
      for (int r = 0; r < 4; ++r) {
        int bl = (wave << 4) + (krow << 2) + r;
        float gi = gbuf[0][bl][col];
        float gf = gbuf[1][bl][col];
        float gg = gbuf[2][bl][col];
        float go = gbuf[3][bl][col];
        float cn = sigm(gf) * cst[r] + sigm(gi) * tanh_f(gg);
        cst[r] = cn;
        float hv = sigm(go) * tanh_f(cn);
        int bg = mb * MB + bl;
        if (jvalid) {
          unsigned short hu = __builtin_bit_cast(unsigned short, (_Float16)hv);
          __hip_atomic_store((unsigned short*)(hdst + (size_t)bg * KP + jj), hu,
                             __ATOMIC_RELAXED, __HIP_MEMORY_SCOPE_AGENT);
        }
        if (isL2) {
          float part = hv * wl;
          part += __shfl_xor(part, 1);
          part += __shfl_xor(part, 2);
          part += __shfl_xor(part, 4);
          part += __shfl_xor(part, 8);
          if (col == 0) atomicAdd(out + (size_t)bg * T_ST + t, part);
        }
      }
    }

    // ---- chunk barrier (64 WGs, flag-per-WG, no RMW, no cache flush) ----
    // release: each wave drains its scoped h-stores, then block-wide barrier,
    // then one relaxed agent store of the phase number.
    asm volatile("s_waitcnt vmcnt(0)" ::: "memory");
    __syncthreads();
    if (tid == 0)
      __hip_atomic_store(&slots[slot_idx], p + 1,
                         __ATOMIC_RELAXED, __HIP_MEMORY_SCOPE_AGENT);
    if (p < T_ST) {
      if (tid < 64) {
        const int* sp = slots + (mb << 6) + tid;   // one slot per lane
        while (__hip_atomic_load(sp, __ATOMIC_RELAXED, __HIP_MEMORY_SCOPE_AGENT) <= p)
          __builtin_amdgcn_s_sleep(1);
      }
      __syncthreads();
    }
  }
}

extern "C" void kernel_launch(void* const* d_in, const int* in_sizes, int n_in,
                              void* d_out, int out_size, void* d_ws, size_t ws_size,
                              hipStream_t stream) {
  (void)in_sizes; (void)n_in; (void)out_size; (void)ws_size;
  const float* x     = (const float*)d_in[0];
  const float* w_ih1 = (const float*)d_in[1];
  const float* w_hh1 = (const float*)d_in[2];
  const float* b_ih1 = (const float*)d_in[3];
  const float* b_hh1 = (const float*)d_in[4];
  const float* w_ih2 = (const float*)d_in[5];
  const float* w_hh2 = (const float*)d_in[6];
  const float* b_ih2 = (const float*)d_in[7];
  const float* b_hh2 = (const float*)d_in[8];
  const float* w_lin = (const float*)d_in[9];
  const float* b_lin = (const float*)d_in[10];
  float* out = (float*)d_out;
  char* ws   = (char*)d_ws;

  hipLaunchKernelGGL(init_kernel, dim3((B_SZ * T_ST + 255) / 256), dim3(256), 0, stream,
                     out, b_lin, (int*)ws);
  hipLaunchKernelGGL(lstm_kernel, dim3(NWG), dim3(256), 0, stream,
                     x, w_ih1, w_hh1, b_ih1, b_hh1,
                     w_ih2, w_hh2, b_ih2, b_hh2,
                     w_lin, out, ws);
}

// Round 4
// 10508.266 us; speedup vs baseline: 2.5799x; 1.3230x over previous
//
#include <hip/hip_runtime.h>
#include <hip/hip_fp16.h>

#define F_DIM 510
#define KP    512      // padded K
#define B_SZ  256
#define T_ST  512
#define MB    64       // batch rows per WG
#define NWG   256

typedef _Float16 h8 __attribute__((ext_vector_type(8)));
typedef float    f4 __attribute__((ext_vector_type(4)));
typedef unsigned long long u64;

__device__ __forceinline__ float sigm(float v)   { return 1.0f / (1.0f + __expf(-v)); }
__device__ __forceinline__ float tanh_f(float v) { return 1.0f - 2.0f / (__expf(2.0f * v) + 1.0f); }

__global__ void init_kernel(float* __restrict__ out, const float* __restrict__ b_lin,
                            int* __restrict__ slots) {
  int i = blockIdx.x * blockDim.x + threadIdx.x;
  if (i < NWG) slots[i] = 0;
  if (i < B_SZ * T_ST) out[i] = b_lin[0];
}

// stage fp32 x [MB][F_DIM] -> LDS fp16 [MB][KP], XOR-swizzled (plain cached loads)
__device__ __forceinline__ void stage_x(char* st, const float* __restrict__ src, int tid) {
  #pragma unroll
  for (int i = 0; i < 16; ++i) {
    int c  = tid + (i << 8);
    int m  = c >> 6;
    int kb = (c & 63) << 3;
    h8 v;
    const float* s = src + m * F_DIM + kb;
    if (kb + 8 <= F_DIM) {
      #pragma unroll
      for (int e = 0; e < 4; ++e) {
        float2 p = *(const float2*)(s + 2 * e);
        v[2 * e]     = (_Float16)p.x;
        v[2 * e + 1] = (_Float16)p.y;
      }
    } else {
      #pragma unroll
      for (int e = 0; e < 8; ++e) v[e] = (_Float16)((kb + e < F_DIM) ? s[e] : 0.0f);
    }
    int byte = ((m * KP + kb) << 1) ^ ((m & 7) << 4);
    *(h8*)(st + byte) = v;
  }
}

// issue 32 pipelined coherent 8B loads into registers (64 KiB tile across 256 threads)
__device__ __forceinline__ void load_h32(u64* v, const u64* __restrict__ src, int tid) {
  #pragma unroll
  for (int i = 0; i < 32; ++i)
    v[i] = __hip_atomic_load(src + tid + (i << 8),
                             __ATOMIC_RELAXED, __HIP_MEMORY_SCOPE_AGENT);
}

// write registers -> LDS fp16 [MB][KP], XOR-swizzled
__device__ __forceinline__ void write_h32(char* st, const u64* v, int tid) {
  #pragma unroll
  for (int i = 0; i < 32; ++i) {
    int c  = tid + (i << 8);
    int m  = c >> 7;          // row 0..63
    int kc = c & 127;         // 8B chunk within 1024B row
    int byte = (m * 1024 + (kc << 3)) ^ ((m & 7) << 4);
    *(u64*)(st + byte) = v[i];
  }
}

__device__ __forceinline__ void gemm_tile(f4* acc, const char* sm, const h8* wf,
                                          int col, int krow) {
  #pragma unroll
  for (int ks = 0; ks < 16; ++ks) {
    #pragma unroll
    for (int mt = 0; mt < 4; ++mt) {
      int lin = mt * 16384 + col * 1024 + ks * 64 + krow * 16;
      h8 af = *(const h8*)(sm + (lin ^ ((col & 7) << 4)));
      acc[mt] = __builtin_amdgcn_mfma_f32_16x16x32_f16(af, wf[ks], acc[mt], 0, 0, 0);
    }
  }
}

__launch_bounds__(256, 1)
__global__ void lstm_kernel(
    const float* __restrict__ x,
    const float* __restrict__ w_ih1, const float* __restrict__ w_hh1,
    const float* __restrict__ b_ih1, const float* __restrict__ b_hh1,
    const float* __restrict__ w_ih2, const float* __restrict__ w_hh2,
    const float* __restrict__ b_ih2, const float* __restrict__ b_hh2,
    const float* __restrict__ w_lin,
    float* __restrict__ out, char* __restrict__ ws)
{
  __shared__ __align__(16) char smem[MB * KP * 2];   // 64 KiB operand stage
  float (*gbuf)[MB][17] = (float (*)[MB][17])smem;   // aliased gate exchange

  int* slots   = (int*)ws;                                        // [NWG]
  _Float16* h1 = (_Float16*)(ws + 1024);                          // [2][B_SZ][KP]
  _Float16* h2 = (_Float16*)(ws + 1024 + 2 * B_SZ * KP * 2);      // [2][B_SZ][KP]

  const int tid  = threadIdx.x;
  const int lane = tid & 63;
  const int wave = tid >> 6;           // wave owns gate type (i,f,g,o)
  const int wg   = blockIdx.x;
  const int xcd   = wg & 7;            // perf heuristic only (round-robin XCD)
  const bool isL2 = (xcd & 1) != 0;
  const int mb    = xcd >> 1;          // batch chunk 0..3
  const int nb    = wg >> 3;           // hidden block 0..31
  const int slot_idx = (mb << 6) + (isL2 ? 32 : 0) + nb;

  const int j0   = nb << 4;
  const int col  = lane & 15;
  const int krow = lane >> 4;
  const int jj   = j0 + col;
  const bool jvalid = (jj < F_DIM);

  const float* wA = isL2 ? w_ih2 : w_ih1;
  const float* wB = isL2 ? w_hh2 : w_hh1;
  const float* bi = isL2 ? b_ih2 : b_ih1;
  const float* bh = isL2 ? b_hh2 : b_hh1;
  const int nrow  = wave * F_DIM + jj;

  // Weights resident in registers as MFMA B-fragments: B[k][n] = W[n][k]
  h8 wfA[16], wfB[16];
  #pragma unroll
  for (int ks = 0; ks < 16; ++ks) {
    h8 a, b;
    #pragma unroll
    for (int e = 0; e < 8; ++e) {
      int k = (ks << 5) + (krow << 3) + e;
      bool ok = jvalid && (k < F_DIM);
      a[e] = (_Float16)(ok ? wA[nrow * F_DIM + k] : 0.0f);
      b[e] = (_Float16)(ok ? wB[nrow * F_DIM + k] : 0.0f);
    }
    wfA[ks] = a; wfB[ks] = b;
  }
  const float bias = jvalid ? (bi[nrow] + bh[nrow]) : 0.0f;

  // cell-update mapping: thread owns (row = tid>>2, cols j0 + (tid&3)*4 .. +3)
  const int urow = tid >> 2;
  const int cg   = tid & 3;
  float wl4[4];
  #pragma unroll
  for (int cc = 0; cc < 4; ++cc) {
    int j = j0 + (cg << 2) + cc;
    wl4[cc] = (isL2 && j < F_DIM) ? w_lin[j] : 0.0f;
  }

  float cst[4] = {0.f, 0.f, 0.f, 0.f};
  u64 va[32], vb[32];

  for (int p = 0; p <= T_ST; ++p) {
    const bool active = isL2 ? (p >= 1) : (p < T_ST);
    if (active) {
      const int t = isL2 ? (p - 1) : p;
      const bool haveR = isL2 ? (p >= 2) : (p >= 1);
      f4 acc[4];
      #pragma unroll
      for (int mt = 0; mt < 4; ++mt) acc[mt] = (f4){bias, bias, bias, bias};

      const u64* h1prev = (const u64*)(h1 + ((size_t)((p - 1) & 1) * B_SZ + mb * MB) * KP);

      if (!isL2) {
        // L1: issue h1(t-1) loads first (latency hides under x staging + GEMM1)
        if (haveR) load_h32(vb, h1prev, tid);
        stage_x(smem, x + ((size_t)t * B_SZ + mb * MB) * F_DIM, tid);
        __syncthreads();
        gemm_tile(acc, smem, wfA, col, krow);
        __syncthreads();
        if (haveR) {
          write_h32(smem, vb, tid);
          __syncthreads();
          gemm_tile(acc, smem, wfB, col, krow);
        }
        __syncthreads();
      } else {
        // L2: issue h1(t) then h2(t-1) loads back-to-back; h2 latency hides
        // under the h1 LDS write + GEMM1.
        const u64* h2prev = (const u64*)(h2 + ((size_t)(p & 1) * B_SZ + mb * MB) * KP);
        load_h32(va, h1prev, tid);
        if (haveR) load_h32(vb, h2prev, tid);
        __builtin_amdgcn_sched_barrier(0);
        write_h32(smem, va, tid);
        __syncthreads();
        gemm_tile(acc, smem, wfA, col, krow);
        __syncthreads();
        if (haveR) {
          write_h32(smem, vb, tid);
          __syncthreads();
          gemm_tile(acc, smem, wfB, col, krow);
        }
        __syncthreads();
      }

      // gate exchange (acc row=(lane>>4)*4+r, col=lane&15 within tile mt)
      #pragma unroll
      for (int mt = 0; mt < 4; ++mt) {
        #pragma unroll
        for (int r = 0; r < 4; ++r)
          gbuf[wave][mt * 16 + (krow << 2) + r][col] = acc[mt][r];
      }
      __syncthreads();

      // cell update: thread -> (urow, 4 cols), one 8B coherent store
      _Float16* hdst = isL2 ? (h2 + (size_t)((p - 1) & 1) * B_SZ * KP)
                            : (h1 + (size_t)(p & 1) * B_SZ * KP);
      float hv4[4];
      #pragma unroll
      for (int cc = 0; cc < 4; ++cc) {
        int c = (cg << 2) + cc;
        float gi = gbuf[0][urow][c];
        float gf = gbuf[1][urow][c];
        float gg = gbuf[2][urow][c];
        float go = gbuf[3][urow][c];
        float cn = sigm(gf) * cst[cc] + sigm(gi) * tanh_f(gg);
        cst[cc] = cn;
        hv4[cc] = sigm(go) * tanh_f(cn);
      }
      u64 hb;
      {
        unsigned int s0 = __builtin_bit_cast(unsigned short, (_Float16)hv4[0]);
        unsigned int s1 = __builtin_bit_cast(unsigned short, (_Float16)hv4[1]);
        unsigned int s2 = __builtin_bit_cast(unsigned short, (_Float16)hv4[2]);
        unsigned int s3 = __builtin_bit_cast(unsigned short, (_Float16)hv4[3]);
        hb = (u64)(s0 | (s1 << 16)) | ((u64)(s2 | (s3 << 16)) << 32);
      }
      int bg = mb * MB + urow;
      __hip_atomic_store((u64*)(hdst + (size_t)bg * KP + j0 + (cg << 2)), hb,
                         __ATOMIC_RELAXED, __HIP_MEMORY_SCOPE_AGENT);
      if (isL2) {
        float part = hv4[0] * wl4[0] + hv4[1] * wl4[1] + hv4[2] * wl4[2] + hv4[3] * wl4[3];
        part += __shfl_xor(part, 1);
        part += __shfl_xor(part, 2);
        if ((tid & 3) == 0) atomicAdd(out + (size_t)bg * T_ST + t, part);
      }
    }

    // ---- chunk barrier (64 WGs, flag-per-WG) ----
    asm volatile("s_waitcnt vmcnt(0)" ::: "memory");
    __syncthreads();
    if (tid == 0)
      __hip_atomic_store(&slots[slot_idx], p + 1,
                         __ATOMIC_RELAXED, __HIP_MEMORY_SCOPE_AGENT);
    if (p < T_ST) {
      if (tid < 64) {
        const int* sp = slots + (mb << 6) + tid;
        while (__hip_atomic_load(sp, __ATOMIC_RELAXED, __HIP_MEMORY_SCOPE_AGENT) <= p)
          __builtin_amdgcn_s_sleep(1);
      }
      __syncthreads();
    }
  }
}

extern "C" void kernel_launch(void* const* d_in, const int* in_sizes, int n_in,
                              void* d_out, int out_size, void* d_ws, size_t ws_size,
                              hipStream_t stream) {
  (void)in_sizes; (void)n_in; (void)out_size; (void)ws_size;
  const float* x     = (const float*)d_in[0];
  const float* w_ih1 = (const float*)d_in[1];
  const float* w_hh1 = (const float*)d_in[2];
  const float* b_ih1 = (const float*)d_in[3];
  const float* b_hh1 = (const float*)d_in[4];
  const float* w_ih2 = (const float*)d_in[5];
  const float* w_hh2 = (const float*)d_in[6];
  const float* b_ih2 = (const float*)d_in[7];
  const float* b_hh2 = (const float*)d_in[8];
  const float* w_lin = (const float*)d_in[9];
  const float* b_lin = (const float*)d_in[10];
  float* out = (float*)d_out;
  char* ws   = (char*)d_ws;

  hipLaunchKernelGGL(init_kernel, dim3((B_SZ * T_ST + 255) / 256), dim3(256), 0, stream,
                     out, b_lin, (int*)ws);
  hipLaunchKernelGGL(lstm_kernel, dim3(NWG), dim3(256), 0, stream,
                     x, w_ih1, w_hh1, b_ih1, b_hh1,
                     w_ih2, w_hh2, b_ih2, b_hh2,
                     w_lin, out, ws);
}

// Round 5
// 9962.556 us; speedup vs baseline: 2.7212x; 1.0548x over previous
//
#include <hip/hip_runtime.h>
#include <hip/hip_fp16.h>

#define F_DIM 510
#define KP    512      // padded K
#define B_SZ  256
#define T_ST  512
#define MB    64       // batch rows per chunk
#define NWG   256
#define R1    8        // h1 ring depth
#define R2    4        // h2 ring depth

typedef _Float16 h8 __attribute__((ext_vector_type(8)));
typedef float    f4 __attribute__((ext_vector_type(4)));
typedef unsigned long long u64;

__device__ __forceinline__ float sigm(float v)   { return 1.0f / (1.0f + __expf(-v)); }
__device__ __forceinline__ float tanh_f(float v) { return 1.0f - 2.0f / (__expf(2.0f * v) + 1.0f); }

__global__ void init_kernel(float* __restrict__ out, const float* __restrict__ b_lin,
                            int* __restrict__ flags) {
  int i = blockIdx.x * blockDim.x + threadIdx.x;
  if (i < NWG) flags[i] = 0;
  if (i < B_SZ * T_ST) out[i] = b_lin[0];
}

// stage fp32 x [MB][F_DIM] -> LDS fp16 [MB][KP], XOR-swizzled (plain cached loads)
__device__ __forceinline__ void stage_x(char* st, const float* __restrict__ src, int tid) {
  #pragma unroll
  for (int i = 0; i < 16; ++i) {
    int c  = tid + (i << 8);
    int m  = c >> 6;
    int kb = (c & 63) << 3;
    h8 v;
    const float* s = src + m * F_DIM + kb;
    if (kb + 8 <= F_DIM) {
      #pragma unroll
      for (int e = 0; e < 4; ++e) {
        float2 p = *(const float2*)(s + 2 * e);
        v[2 * e]     = (_Float16)p.x;
        v[2 * e + 1] = (_Float16)p.y;
      }
    } else {
      #pragma unroll
      for (int e = 0; e < 8; ++e) v[e] = (_Float16)((kb + e < F_DIM) ? s[e] : 0.0f);
    }
    int byte = ((m * KP + kb) << 1) ^ ((m & 7) << 4);
    *(h8*)(st + byte) = v;
  }
}

// issue 32 pipelined coherent 8B loads into registers (64 KiB tile across 256 threads)
__device__ __forceinline__ void load_h32(u64* v, const u64* __restrict__ src, int tid) {
  #pragma unroll
  for (int i = 0; i < 32; ++i)
    v[i] = __hip_atomic_load(src + tid + (i << 8),
                             __ATOMIC_RELAXED, __HIP_MEMORY_SCOPE_AGENT);
}

// write registers -> LDS fp16 [MB][KP], XOR-swizzled
__device__ __forceinline__ void write_h32(char* st, const u64* v, int tid) {
  #pragma unroll
  for (int i = 0; i < 32; ++i) {
    int c  = tid + (i << 8);
    int m  = c >> 7;          // row 0..63
    int kc = c & 127;         // 8B chunk within 1024B row
    int byte = (m * 1024 + (kc << 3)) ^ ((m & 7) << 4);
    *(u64*)(st + byte) = v[i];
  }
}

__device__ __forceinline__ void gemm_tile(f4* acc, const char* sm, const h8* wf,
                                          int col, int krow) {
  #pragma unroll
  for (int ks = 0; ks < 16; ++ks) {
    #pragma unroll
    for (int mt = 0; mt < 4; ++mt) {
      int lin = mt * 16384 + col * 1024 + ks * 64 + krow * 16;
      h8 af = *(const h8*)(sm + (lin ^ ((col & 7) << 4)));
      acc[mt] = __builtin_amdgcn_mfma_f32_16x16x32_f16(af, wf[ks], acc[mt], 0, 0, 0);
    }
  }
}

// all-wave poll: lane<32 watches the 32 L1 flags (>= thr_lo), lane>=32 the 32 L2
// flags (>= thr_hi). Returns when the whole 64-flag vector satisfies thresholds.
__device__ __forceinline__ void poll_flags(const int* fl, int thr_lo, int thr_hi, int lane) {
  const int thr = (lane < 32) ? thr_lo : thr_hi;
  const int* p = fl + lane;
  while (true) {
    int v = __hip_atomic_load(p, __ATOMIC_RELAXED, __HIP_MEMORY_SCOPE_AGENT);
    if (__all(v >= thr)) break;
    __builtin_amdgcn_s_sleep(1);
  }
}

__launch_bounds__(256, 1)
__global__ void lstm_kernel(
    const float* __restrict__ x,
    const float* __restrict__ w_ih1, const float* __restrict__ w_hh1,
    const float* __restrict__ b_ih1, const float* __restrict__ b_hh1,
    const float* __restrict__ w_ih2, const float* __restrict__ w_hh2,
    const float* __restrict__ b_ih2, const float* __restrict__ b_hh2,
    const float* __restrict__ w_lin,
    float* __restrict__ out, char* __restrict__ ws)
{
  __shared__ __align__(16) char smem[MB * KP * 2];   // 64 KiB operand stage
  float (*gbuf)[MB][17] = (float (*)[MB][17])smem;   // aliased gate exchange

  int* flags   = (int*)ws;                                        // [4][64]
  _Float16* h1 = (_Float16*)(ws + 4096);                          // [R1][B_SZ][KP]
  _Float16* h2 = (_Float16*)(ws + 4096 + (size_t)R1 * B_SZ * KP * 2);  // [R2][B_SZ][KP]

  const int tid  = threadIdx.x;
  const int lane = tid & 63;
  const int wave = tid >> 6;           // wave owns gate type (i,f,g,o)
  const int wg   = blockIdx.x;
  const int xcd   = wg & 7;            // perf heuristic only (round-robin XCD)
  const bool isL2 = (xcd & 1) != 0;
  const int mb    = xcd >> 1;          // batch chunk 0..3
  const int nb    = wg >> 3;           // hidden block 0..31
  int* flags_c    = flags + (mb << 6);
  const int my_flag = (mb << 6) + (isL2 ? 32 : 0) + nb;

  const int j0   = nb << 4;
  const int col  = lane & 15;
  const int krow = lane >> 4;
  const int jj   = j0 + col;
  const bool jvalid = (jj < F_DIM);

  const float* wA = isL2 ? w_ih2 : w_ih1;
  const float* wB = isL2 ? w_hh2 : w_hh1;
  const float* bi = isL2 ? b_ih2 : b_ih1;
  const float* bh = isL2 ? b_hh2 : b_hh1;
  const int nrow  = wave * F_DIM + jj;

  // Weights resident in registers as MFMA B-fragments: B[k][n] = W[n][k]
  h8 wfA[16], wfB[16];
  #pragma unroll
  for (int ks = 0; ks < 16; ++ks) {
    h8 a, b;
    #pragma unroll
    for (int e = 0; e < 8; ++e) {
      int k = (ks << 5) + (krow << 3) + e;
      bool ok = jvalid && (k < F_DIM);
      a[e] = (_Float16)(ok ? wA[nrow * F_DIM + k] : 0.0f);
      b[e] = (_Float16)(ok ? wB[nrow * F_DIM + k] : 0.0f);
    }
    wfA[ks] = a; wfB[ks] = b;
  }
  const float bias = jvalid ? (bi[nrow] + bh[nrow]) : 0.0f;

  // cell-update mapping: thread owns (row = tid>>2, cols j0 + (tid&3)*4 .. +3)
  const int urow = tid >> 2;
  const int cg   = tid & 3;
  float wl4[4];
  #pragma unroll
  for (int cc = 0; cc < 4; ++cc) {
    int j = j0 + (cg << 2) + cc;
    wl4[cc] = (isL2 && j < F_DIM) ? w_lin[j] : 0.0f;
  }

  float cst[4] = {0.f, 0.f, 0.f, 0.f};
  u64 va[32], vb[32];

  for (int t = 0; t < T_ST; ++t) {
    f4 acc[4];
    #pragma unroll
    for (int mt = 0; mt < 4; ++mt) acc[mt] = (f4){bias, bias, bias, bias};

    if (!isL2) {
      // ---- L1 step t: h1(t) = cell(x(t) Wih + h1(t-1) Whh) ----
      stage_x(smem, x + ((size_t)t * B_SZ + mb * MB) * F_DIM, tid);
      // need: L1 peers done step t-1 (flag>=t); L2 done step t-8 (flag>=t-7, slot reuse)
      poll_flags(flags_c, t, t - 7, lane);
      if (t > 0)
        load_h32(vb, (const u64*)(h1 + ((size_t)((t - 1) % R1) * B_SZ + mb * MB) * KP), tid);
      __builtin_amdgcn_sched_barrier(0);
      __syncthreads();
      gemm_tile(acc, smem, wfA, col, krow);   // h1 load latency hides here
      __syncthreads();
      if (t > 0) {
        write_h32(smem, vb, tid);
        __syncthreads();
        gemm_tile(acc, smem, wfB, col, krow);
      }
      __syncthreads();
    } else {
      // ---- L2 step t: h2(t) = cell(h1(t) Wih2 + h2(t-1) Whh2) ----
      // need: L1 done step t (flag>=t+1); L2 peers done step t-1 (flag>=t)
      poll_flags(flags_c, t + 1, t, lane);
      load_h32(va, (const u64*)(h1 + ((size_t)(t % R1) * B_SZ + mb * MB) * KP), tid);
      if (t > 0)
        load_h32(vb, (const u64*)(h2 + ((size_t)((t - 1) % R2) * B_SZ + mb * MB) * KP), tid);
      __builtin_amdgcn_sched_barrier(0);
      write_h32(smem, va, tid);
      __syncthreads();
      gemm_tile(acc, smem, wfA, col, krow);   // h2 load latency hides here
      __syncthreads();
      if (t > 0) {
        write_h32(smem, vb, tid);
        __syncthreads();
        gemm_tile(acc, smem, wfB, col, krow);
      }
      __syncthreads();
    }

    // gate exchange (acc row=(lane>>4)*4+r, col=lane&15 within tile mt)
    #pragma unroll
    for (int mt = 0; mt < 4; ++mt) {
      #pragma unroll
      for (int r = 0; r < 4; ++r)
        gbuf[wave][mt * 16 + (krow << 2) + r][col] = acc[mt][r];
    }
    __syncthreads();

    // cell update: thread -> (urow, 4 cols), one 8B coherent store into ring
    _Float16* hdst = isL2 ? (h2 + (size_t)(t % R2) * B_SZ * KP)
                          : (h1 + (size_t)(t % R1) * B_SZ * KP);
    float hv4[4];
    #pragma unroll
    for (int cc = 0; cc < 4; ++cc) {
      int c = (cg << 2) + cc;
      float gi = gbuf[0][urow][c];
      float gf = gbuf[1][urow][c];
      float gg = gbuf[2][urow][c];
      float go = gbuf[3][urow][c];
      float cn = sigm(gf) * cst[cc] + sigm(gi) * tanh_f(gg);
      cst[cc] = cn;
      hv4[cc] = sigm(go) * tanh_f(cn);
    }
    u64 hb;
    {
      unsigned int s0 = __builtin_bit_cast(unsigned short, (_Float16)hv4[0]);
      unsigned int s1 = __builtin_bit_cast(unsigned short, (_Float16)hv4[1]);
      unsigned int s2 = __builtin_bit_cast(unsigned short, (_Float16)hv4[2]);
      unsigned int s3 = __builtin_bit_cast(unsigned short, (_Float16)hv4[3]);
      hb = (u64)(s0 | (s1 << 16)) | ((u64)(s2 | (s3 << 16)) << 32);
    }
    int bg = mb * MB + urow;
    __hip_atomic_store((u64*)(hdst + (size_t)bg * KP + j0 + (cg << 2)), hb,
                       __ATOMIC_RELAXED, __HIP_MEMORY_SCOPE_AGENT);

    // release: drain own h stores, block-wide join, publish progress
    asm volatile("s_waitcnt vmcnt(0)" ::: "memory");
    __syncthreads();
    if (tid == 0)
      __hip_atomic_store(&flags[my_flag], t + 1,
                         __ATOMIC_RELAXED, __HIP_MEMORY_SCOPE_AGENT);

    // contended output atomics AFTER the flag -> off the critical path
    if (isL2) {
      float part = hv4[0] * wl4[0] + hv4[1] * wl4[1] + hv4[2] * wl4[2] + hv4[3] * wl4[3];
      part += __shfl_xor(part, 1);
      part += __shfl_xor(part, 2);
      if ((tid & 3) == 0) atomicAdd(out + (size_t)bg * T_ST + t, part);
    }
  }
}

extern "C" void kernel_launch(void* const* d_in, const int* in_sizes, int n_in,
                              void* d_out, int out_size, void* d_ws, size_t ws_size,
                              hipStream_t stream) {
  (void)in_sizes; (void)n_in; (void)out_size; (void)ws_size;
  const float* x     = (const float*)d_in[0];
  const float* w_ih1 = (const float*)d_in[1];
  const float* w_hh1 = (const float*)d_in[2];
  const float* b_ih1 = (const float*)d_in[3];
  const float* b_hh1 = (const float*)d_in[4];
  const float* w_ih2 = (const float*)d_in[5];
  const float* w_hh2 = (const float*)d_in[6];
  const float* b_ih2 = (const float*)d_in[7];
  const float* b_hh2 = (const float*)d_in[8];
  const float* w_lin = (const float*)d_in[9];
  const float* b_lin = (const float*)d_in[10];
  float* out = (float*)d_out;
  char* ws   = (char*)d_ws;

  hipLaunchKernelGGL(init_kernel, dim3((B_SZ * T_ST + 255) / 256), dim3(256), 0, stream,
                     out, b_lin, (int*)ws);
  hipLaunchKernelGGL(lstm_kernel, dim3(NWG), dim3(256), 0, stream,
                     x, w_ih1, w_hh1, b_ih1, b_hh1,
                     w_ih2, w_hh2, b_ih2, b_hh2,
                     w_lin, out, ws);
}